// Round 1
// baseline (2680.059 us; speedup 1.0000x reference)
//
#include <hip/hip_runtime.h>

#define HID   51
#define G4    204           // 4*HID
#define SEQT  999
#define EPB   8             // batch elements per block
#define CH    111           // time chunk (999 = 9*111)
#define NTH   256

__launch_bounds__(NTH, 2)
__global__ void lstm_kernel(const float* __restrict__ x,
                            const float* __restrict__ W_ih,
                            const float* __restrict__ W_hh,
                            const float* __restrict__ b_ih,
                            const float* __restrict__ b_hh,
                            const float* __restrict__ W_fc,
                            const float* __restrict__ b_fc,
                            float* __restrict__ out)
{
    __shared__ __align__(16) float h_lds[HID * EPB];   // [u][e], e stride 1
    __shared__ __align__(16) float gbuf[EPB * G4];     // [e][r] -> conflict-free r-major access
    __shared__ __align__(16) float x_lds[CH * EPB];    // [tt][e]
    __shared__ __align__(16) float y_lds[CH * EPB];    // [tt][e]
    __shared__ float wfc_lds[HID];
    __shared__ float bfc_lds;

    const int tid = threadIdx.x;
    const int e0  = blockIdx.x * EPB;

    // ---- one-time weight load: thread r < 204 owns gate row r in registers ----
    float w[HID];
    float wih_r = 0.f, b_r = 0.f;
    if (tid < G4) {
        wih_r = W_ih[tid];
        b_r   = b_ih[tid] + b_hh[tid];
#pragma unroll
        for (int k = 0; k < HID; ++k) w[k] = W_hh[tid * HID + k];
    }
    if (tid < HID) wfc_lds[tid] = W_fc[tid];
    if (tid == 0)  bfc_lds = b_fc[0];
    for (int i = tid; i < HID * EPB; i += NTH) h_lds[i] = 0.f;

    // ---- phase-C ownership: thread < 204 owns (unit cu, elems ce, ce+1) ----
    const int  cu  = (tid < G4) ? (tid % HID) : 0;
    const int  ce  = (tid < G4) ? ((tid / HID) * 2) : 0;
    float c0 = 0.f, c1 = 0.f;

    const bool isg = (tid >= 2 * HID) && (tid < 3 * HID);   // g-gate rows use tanh
    const float K1 = 1.442695040889f;                        // log2(e)

    __syncthreads();

#pragma unroll 1
    for (int t0 = 0; t0 < SEQT; t0 += CH) {
        // ---- stage x chunk (coalesced: consecutive tid -> consecutive t) ----
#pragma unroll
        for (int i = 0; i < (CH * EPB + NTH - 1) / NTH; ++i) {
            int idx = i * NTH + tid;
            if (idx < CH * EPB) {
                int e = idx / CH, tt = idx % CH;
                x_lds[tt * EPB + e] = x[(e0 + e) * SEQT + t0 + tt];
            }
        }
        __syncthreads();

#pragma unroll 1
        for (int tt = 0; tt < CH; ++tt) {
            // ---------- phase A: gates for 8 elements, weights in regs ----------
            if (tid < G4) {
                const float4 xa = *(const float4*)&x_lds[tt * EPB];
                const float4 xb = *(const float4*)&x_lds[tt * EPB + 4];
                float a[EPB];
                a[0] = fmaf(xa.x, wih_r, b_r);
                a[1] = fmaf(xa.y, wih_r, b_r);
                a[2] = fmaf(xa.z, wih_r, b_r);
                a[3] = fmaf(xa.w, wih_r, b_r);
                a[4] = fmaf(xb.x, wih_r, b_r);
                a[5] = fmaf(xb.y, wih_r, b_r);
                a[6] = fmaf(xb.z, wih_r, b_r);
                a[7] = fmaf(xb.w, wih_r, b_r);
#pragma unroll
                for (int k = 0; k < HID; ++k) {
                    const float4 ha = *(const float4*)&h_lds[k * EPB];
                    const float4 hb = *(const float4*)&h_lds[k * EPB + 4];
                    const float wk = w[k];
                    a[0] = fmaf(wk, ha.x, a[0]);
                    a[1] = fmaf(wk, ha.y, a[1]);
                    a[2] = fmaf(wk, ha.z, a[2]);
                    a[3] = fmaf(wk, ha.w, a[3]);
                    a[4] = fmaf(wk, hb.x, a[4]);
                    a[5] = fmaf(wk, hb.y, a[5]);
                    a[6] = fmaf(wk, hb.z, a[6]);
                    a[7] = fmaf(wk, hb.w, a[7]);
                }
                // activation: sigmoid for i,f,o; tanh for g (tanh(x)=2*sig(2x)-1)
#pragma unroll
                for (int e = 0; e < EPB; ++e) {
                    float xv = a[e];
                    float xm = isg ? (2.0f * xv) : xv;
                    float ex = __builtin_amdgcn_exp2f(-K1 * xm);
                    float s  = __builtin_amdgcn_rcpf(1.0f + ex);
                    float v  = isg ? (2.0f * s - 1.0f) : s;
                    gbuf[e * G4 + tid] = v;       // [e][r]: lanes consecutive -> no conflict
                }
            }
            __syncthreads();

            // ---------- phase C: c/h update, c in registers ----------
            if (tid < G4) {
                {
                    const int gb = ce * G4;
                    float I = gbuf[gb + cu];
                    float F = gbuf[gb + HID + cu];
                    float G = gbuf[gb + 2 * HID + cu];
                    float O = gbuf[gb + 3 * HID + cu];
                    c0 = fmaf(F, c0, I * G);
                    float ex = __builtin_amdgcn_exp2f(-2.0f * K1 * c0);
                    float th = 2.0f * __builtin_amdgcn_rcpf(1.0f + ex) - 1.0f;
                    h_lds[cu * EPB + ce] = O * th;
                }
                {
                    const int gb = (ce + 1) * G4;
                    float I = gbuf[gb + cu];
                    float F = gbuf[gb + HID + cu];
                    float G = gbuf[gb + 2 * HID + cu];
                    float O = gbuf[gb + 3 * HID + cu];
                    c1 = fmaf(F, c1, I * G);
                    float ex = __builtin_amdgcn_exp2f(-2.0f * K1 * c1);
                    float th = 2.0f * __builtin_amdgcn_rcpf(1.0f + ex) - 1.0f;
                    h_lds[cu * EPB + ce + 1] = O * th;
                }
            }
            __syncthreads();

            // ---------- y = W_fc . h + b_fc  (wave 0, 8 lanes per element) ----------
            if (tid < 64) {
                const int ye = tid >> 3, yi = tid & 7;
                float p = 0.f;
#pragma unroll
                for (int u = 0; u < HID; u += 8) {
                    int uu = u + yi;
                    if (uu < HID) p = fmaf(h_lds[uu * EPB + ye], wfc_lds[uu], p);
                }
                p += __shfl_xor(p, 1);
                p += __shfl_xor(p, 2);
                p += __shfl_xor(p, 4);
                if (yi == 0) y_lds[tt * EPB + ye] = p + bfc_lds;
            }
        }
        __syncthreads();

        // ---- flush y chunk (coalesced) ----
#pragma unroll
        for (int i = 0; i < (CH * EPB + NTH - 1) / NTH; ++i) {
            int idx = i * NTH + tid;
            if (idx < CH * EPB) {
                int e = idx / CH, tt = idx % CH;
                out[(e0 + e) * SEQT + t0 + tt] = y_lds[tt * EPB + e];
            }
        }
        __syncthreads();
    }
}

extern "C" void kernel_launch(void* const* d_in, const int* in_sizes, int n_in,
                              void* d_out, int out_size, void* d_ws, size_t ws_size,
                              hipStream_t stream) {
    const float* x    = (const float*)d_in[0];
    const float* W_ih = (const float*)d_in[1];
    const float* W_hh = (const float*)d_in[2];
    const float* b_ih = (const float*)d_in[3];
    const float* b_hh = (const float*)d_in[4];
    const float* W_fc = (const float*)d_in[5];
    const float* b_fc = (const float*)d_in[6];
    float* out = (float*)d_out;

    dim3 grid(4096 / EPB);   // 512 blocks, 8 batch elements each
    dim3 block(NTH);
    lstm_kernel<<<grid, block, 0, stream>>>(x, W_ih, W_hh, b_ih, b_hh, W_fc, b_fc, out);
}

// Round 2
// 796.540 us; speedup vs baseline: 3.3646x; 3.3646x over previous
//
#include <hip/hip_runtime.h>
#include <hip/hip_bf16.h>

#define HID   51
#define MR    208          // 204 gate rows padded to 13 tiles of 16
#define SEQT  999
#define CH    111          // 999 = 9 * 111
#define NCH   9
#define EPB   16           // batch elements per block (MFMA N)
#define NTH   256

typedef __attribute__((ext_vector_type(8))) short  short8;   // 8 bf16 = 4 VGPRs
typedef __attribute__((ext_vector_type(4))) float  floatx4;

// Build A_ext[208][64] bf16: dest row r = 4u+gate  <-  W_hh[gate*51+u][k].
// k>=51 and u>=51 are zero. Gate-interleaved rows make the MFMA C-layout
// deliver (i,f,g,o) of one unit into one lane's 4 accumulator regs.
__global__ void prep_kernel(const float* __restrict__ W_hh,
                            __hip_bfloat16* __restrict__ A_ext)
{
    int idx = blockIdx.x * blockDim.x + threadIdx.x;
    if (idx >= MR * 64) return;
    int r = idx >> 6, k = idx & 63;
    int u = r >> 2, gate = r & 3;
    float v = 0.f;
    if (u < HID && k < HID) v = W_hh[(gate * HID + u) * HID + k];
    A_ext[idx] = __float2bfloat16(v);
}

__launch_bounds__(NTH)
__global__ void lstm_mfma_kernel(const float* __restrict__ x,
                                 const float* __restrict__ W_ih,
                                 const float* __restrict__ b_ih,
                                 const float* __restrict__ b_hh,
                                 const float* __restrict__ W_fc,
                                 const float* __restrict__ b_fc,
                                 const __hip_bfloat16* __restrict__ A_ext,
                                 float* __restrict__ out)
{
    // bcol[buf][e*72 + k] bf16: B-operand column buffer (h in rows 0..50,
    // rows 51..63 stay 0). Row stride 72 halves = 144 B (16B-aligned, and
    // bank-rotates by 4 per elem -> 2-way conflicts only, which are free).
    __shared__ __hip_bfloat16 bcol[2][EPB * 72];
    __shared__ float x_lds[CH * 17];     // [tt][e], pad 17 kills staging conflicts
    __shared__ float y_lds[CH * 17];
    __shared__ float ypart[2][4][EPB];   // per-wave fc partials, double-buffered

    const int tid  = threadIdx.x;
    const int w    = tid >> 6;
    const int lane = tid & 63;
    const int e    = lane & 15;   // elem (MFMA col)
    const int g4   = lane >> 4;   // lane group
    const int e0   = blockIdx.x * EPB;

    // tile split over 4 waves: wave w owns tiles {w, w+4, w+8, (w+12)<13}
    const int nt = (w == 0) ? 4 : 3;

    short8  Afrag[4][2];       // [tile][K-half] W_hh fragments (live whole kernel)
    floatx4 wihq[4], bq[4];    // fp32 x-weight and bias quads (exact, post-MFMA)
    float   wfc_r[4];
    float   cst[4];            // cell state, register-resident per (unit, elem)
    int     uu[4];

#pragma unroll
    for (int i = 0; i < 4; ++i) {
        floatx4 wv = {0.f, 0.f, 0.f, 0.f}, bv = {0.f, 0.f, 0.f, 0.f};
        float wf = 0.f;
        int T = w + 4 * i;
        int u = T * 4 + g4;
        if (i < nt) {
            int m = T * 16 + e;
#pragma unroll
            for (int kk = 0; kk < 2; ++kk)
                Afrag[i][kk] = *(const short8*)&A_ext[m * 64 + kk * 32 + g4 * 8];
            if (u < HID) {
#pragma unroll
                for (int gg = 0; gg < 4; ++gg) {
                    wv[gg] = W_ih[gg * HID + u];
                    bv[gg] = b_ih[gg * HID + u] + b_hh[gg * HID + u];
                }
                wf = W_fc[u];
            }
        } else {
            u = HID;
        }
        uu[i] = u; wihq[i] = wv; bq[i] = bv; wfc_r[i] = wf; cst[i] = 0.f;
    }

    // init both bcol buffers to 0 (h0 = 0; rows 51..71 must stay 0 forever)
    for (int i = tid; i < EPB * 72; i += NTH) {
        bcol[0][i] = __float2bfloat16(0.f);
        bcol[1][i] = __float2bfloat16(0.f);
    }
    const float bfc = b_fc[0];
    const float K1  = 1.442695040889f;   // log2(e)

    __syncthreads();

    for (int tc = 0; tc < NCH; ++tc) {
        const int t0 = tc * CH;
        // ---- stage x chunk (coalesced: consecutive tid -> consecutive t) ----
        for (int i2 = tid; i2 < CH * EPB; i2 += NTH) {
            int ee = i2 / CH, tt = i2 % CH;
            x_lds[tt * 17 + ee] = x[(size_t)(e0 + ee) * SEQT + t0 + tt];
        }
        __syncthreads();

        for (int tt = 0; tt < CH; ++tt) {
            const int t  = t0 + tt;
            const int rp = t & 1, wp = rp ^ 1;

            // ---- B fragments: h_{t-1} column, one b128 per K-half ----
            short8 B0 = *(const short8*)&bcol[rp][e * 72 + g4 * 8];
            short8 B1 = *(const short8*)&bcol[rp][e * 72 + 32 + g4 * 8];
            const float xe = x_lds[tt * 17 + e];

            float py = 0.f;
#pragma unroll
            for (int i = 0; i < 4; ++i) {
                if (i < nt) {
                    floatx4 acc = {0.f, 0.f, 0.f, 0.f};
                    acc = __builtin_amdgcn_mfma_f32_16x16x32_bf16(Afrag[i][0], B0, acc, 0, 0, 0);
                    acc = __builtin_amdgcn_mfma_f32_16x16x32_bf16(Afrag[i][1], B1, acc, 0, 0, 0);
                    // exact fp32 x-term and bias (reg 0..3 = i,f,g,o of unit uu[i])
                    float pi = fmaf(xe, wihq[i][0], acc[0] + bq[i][0]);
                    float pf = fmaf(xe, wihq[i][1], acc[1] + bq[i][1]);
                    float pg = fmaf(xe, wihq[i][2], acc[2] + bq[i][2]);
                    float po = fmaf(xe, wihq[i][3], acc[3] + bq[i][3]);
                    float si = __builtin_amdgcn_rcpf(1.f + __builtin_amdgcn_exp2f(-K1 * pi));
                    float sf = __builtin_amdgcn_rcpf(1.f + __builtin_amdgcn_exp2f(-K1 * pf));
                    float sg = 2.f * __builtin_amdgcn_rcpf(1.f + __builtin_amdgcn_exp2f(-2.f * K1 * pg)) - 1.f;
                    float so = __builtin_amdgcn_rcpf(1.f + __builtin_amdgcn_exp2f(-K1 * po));
                    float c  = fmaf(sf, cst[i], si * sg);
                    cst[i] = c;
                    float th = 2.f * __builtin_amdgcn_rcpf(1.f + __builtin_amdgcn_exp2f(-2.f * K1 * c)) - 1.f;
                    float h  = so * th;
                    py = fmaf(wfc_r[i], h, py);
                    if (uu[i] < HID)
                        bcol[wp][e * 72 + uu[i]] = __float2bfloat16(h);
                }
            }

            // ---- fc partial: reduce over lane groups, stash per wave ----
            py += __shfl_xor(py, 16);
            py += __shfl_xor(py, 32);
            if (lane < EPB) ypart[wp][w][lane] = py;

            __syncthreads();   // the ONE barrier per step

            // finalize y_t (reads this step's ypart[wp]; next step writes ypart[rp])
            if (w == 0 && lane < EPB)
                y_lds[tt * 17 + lane] = ypart[wp][0][lane] + ypart[wp][1][lane]
                                      + ypart[wp][2][lane] + ypart[wp][3][lane] + bfc;
        }
        __syncthreads();

        // ---- flush y chunk (coalesced) ----
        for (int i2 = tid; i2 < CH * EPB; i2 += NTH) {
            int ee = i2 / CH, tt = i2 % CH;
            out[(size_t)(e0 + ee) * SEQT + t0 + tt] = y_lds[tt * 17 + ee];
        }
        __syncthreads();
    }
}

extern "C" void kernel_launch(void* const* d_in, const int* in_sizes, int n_in,
                              void* d_out, int out_size, void* d_ws, size_t ws_size,
                              hipStream_t stream) {
    const float* x    = (const float*)d_in[0];
    const float* W_ih = (const float*)d_in[1];
    const float* W_hh = (const float*)d_in[2];
    const float* b_ih = (const float*)d_in[3];
    const float* b_hh = (const float*)d_in[4];
    const float* W_fc = (const float*)d_in[5];
    const float* b_fc = (const float*)d_in[6];
    float* out = (float*)d_out;

    __hip_bfloat16* A_ext = (__hip_bfloat16*)d_ws;   // 208*64*2 = 26.6 KB

    prep_kernel<<<(MR * 64 + NTH - 1) / NTH, NTH, 0, stream>>>(W_hh, A_ext);
    lstm_mfma_kernel<<<4096 / EPB, NTH, 0, stream>>>(x, W_ih, b_ih, b_hh,
                                                     W_fc, b_fc, A_ext, out);
}

// Round 3
// 608.869 us; speedup vs baseline: 4.4017x; 1.3082x over previous
//
#include <hip/hip_runtime.h>
#include <hip/hip_bf16.h>

#define HID   51
#define MR    208          // 204 gate rows padded to 13 tiles of 16
#define SEQT  999
#define CH    111          // 999 = 9 * 111
#define NCH   9
#define EPB   16           // batch elements per block (MFMA N)
#define NTW   13           // tile waves (one 16-row tile each)
#define NTH   896          // 13 tile waves + 1 y-finalizer wave

typedef __attribute__((ext_vector_type(8))) short  short8;   // 8 bf16 = 4 VGPRs
typedef __attribute__((ext_vector_type(4))) float  floatx4;

// A_ext[208][64] bf16, row r = 4u+gate <- W_hh[gate*51+u][k], PRE-SCALED by
// -log2(e) (gates i,f,o) or -2*log2(e) (gate g) so MFMA directly produces
// exp2 arguments. Gate-interleaved rows put (i,f,g,o) of one unit into one
// lane's 4 accumulator regs (C layout: row=(lane>>4)*4+reg, col=lane&15).
__global__ void prep_kernel(const float* __restrict__ W_hh,
                            __hip_bfloat16* __restrict__ A_ext)
{
    const float K1 = 1.442695040889f;
    int idx = blockIdx.x * blockDim.x + threadIdx.x;
    if (idx >= MR * 64) return;
    int r = idx >> 6, k = idx & 63;
    int u = r >> 2, gate = r & 3;
    float v = 0.f;
    if (u < HID && k < HID) {
        float s = (gate == 2) ? (-2.f * K1) : (-K1);
        v = s * W_hh[(gate * HID + u) * HID + k];
    }
    A_ext[idx] = __float2bfloat16(v);
}

__launch_bounds__(NTH)
__global__ void lstm_mfma_kernel(const float* __restrict__ x,
                                 const float* __restrict__ W_ih,
                                 const float* __restrict__ b_ih,
                                 const float* __restrict__ b_hh,
                                 const float* __restrict__ W_fc,
                                 const float* __restrict__ b_fc,
                                 const __hip_bfloat16* __restrict__ A_ext,
                                 float* __restrict__ out)
{
    // bcol[buf][e*72 + k] bf16: B-operand column buffer (h rows 0..50, rest 0).
    // Row stride 72 halves = 144 B (16B-aligned, bank-rotate 4/elem -> only
    // free 2-way conflicts on the b128 fragment reads).
    __shared__ __hip_bfloat16 bcol[2][EPB * 72];
    __shared__ float x_lds[CH * 17];      // [tt][e], pad 17
    __shared__ float y_lds[CH * 17];
    __shared__ float ypart[2][NTW][EPB];  // per-wave fc partials, double-buffered

    const int tid  = threadIdx.x;
    const int w    = tid >> 6;    // wave id: 0..12 tiles, 13 = y-finalizer
    const int lane = tid & 63;
    const int e    = lane & 15;   // elem (MFMA col / A row)
    const int g4   = lane >> 4;   // lane group
    const int e0   = blockIdx.x * EPB;
    const int u    = 4 * w + g4;  // this lane's hidden unit (tile waves)
    const bool tw  = (w < NTW);
    const bool uok = tw && (u < HID);

    const float K1 = 1.442695040889f;

    short8  Afrag0 = {0,0,0,0,0,0,0,0}, Afrag1 = {0,0,0,0,0,0,0,0};
    floatx4 wihq = {0.f, 0.f, 0.f, 0.f}, bq = {0.f, 0.f, 0.f, 0.f};
    float   wfc_r = 0.f;
    float   cst = 0.f;

    if (tw) {
        int m = w * 16 + e;                       // A row
        Afrag0 = *(const short8*)&A_ext[m * 64 + g4 * 8];
        Afrag1 = *(const short8*)&A_ext[m * 64 + 32 + g4 * 8];
        if (u < HID) {
#pragma unroll
            for (int gg = 0; gg < 4; ++gg) {
                float s = (gg == 2) ? (-2.f * K1) : (-K1);
                wihq[gg] = s * W_ih[gg * HID + u];
                bq[gg]   = s * (b_ih[gg * HID + u] + b_hh[gg * HID + u]);
            }
            wfc_r = W_fc[u];
        }
    }

    for (int i = tid; i < EPB * 72; i += NTH) {
        bcol[0][i] = __float2bfloat16(0.f);
        bcol[1][i] = __float2bfloat16(0.f);
    }
    const float bfc = b_fc[0];

    __syncthreads();

    for (int tc = 0; tc < NCH; ++tc) {
        const int t0 = tc * CH;
        for (int i2 = tid; i2 < CH * EPB; i2 += NTH) {
            int ee = i2 / CH, tt = i2 % CH;
            x_lds[tt * 17 + ee] = x[(size_t)(e0 + ee) * SEQT + t0 + tt];
        }
        __syncthreads();

        for (int tt = 0; tt < CH; ++tt) {
            const int t  = t0 + tt;
            const int rp = t & 1, wp = rp ^ 1;

            if (tw) {
                short8 B0 = *(const short8*)&bcol[rp][e * 72 + g4 * 8];
                short8 B1 = *(const short8*)&bcol[rp][e * 72 + 32 + g4 * 8];
                const float xe = x_lds[tt * 17 + e];

                floatx4 acc = {0.f, 0.f, 0.f, 0.f};
                acc = __builtin_amdgcn_mfma_f32_16x16x32_bf16(Afrag0, B0, acc, 0, 0, 0);
                acc = __builtin_amdgcn_mfma_f32_16x16x32_bf16(Afrag1, B1, acc, 0, 0, 0);
                // regs 0..3 = (-K1 or -2K1)-scaled pre-activations i,f,g,o
                float pi = fmaf(xe, wihq[0], acc[0] + bq[0]);
                float pf = fmaf(xe, wihq[1], acc[1] + bq[1]);
                float pg = fmaf(xe, wihq[2], acc[2] + bq[2]);
                float po = fmaf(xe, wihq[3], acc[3] + bq[3]);
                float si = __builtin_amdgcn_rcpf(1.f + __builtin_amdgcn_exp2f(pi));
                float sf = __builtin_amdgcn_rcpf(1.f + __builtin_amdgcn_exp2f(pf));
                float sg = 2.f * __builtin_amdgcn_rcpf(1.f + __builtin_amdgcn_exp2f(pg)) - 1.f;
                float so = __builtin_amdgcn_rcpf(1.f + __builtin_amdgcn_exp2f(po));
                float c  = fmaf(sf, cst, si * sg);
                cst = c;
                float th = 2.f * __builtin_amdgcn_rcpf(1.f + __builtin_amdgcn_exp2f(-2.f * K1 * c)) - 1.f;
                float h  = so * th;
                if (uok) bcol[wp][e * 72 + u] = __float2bfloat16(h);

                float py = wfc_r * h;
                py += __shfl_xor(py, 16);
                py += __shfl_xor(py, 32);
                if (lane < EPB) ypart[wp][w][lane] = py;
            } else if (lane < EPB) {
                // y-finalizer: reduce LAST step's partials (post-barrier below
                // it reads this step's). First iteration reads zeros? No:
                // handled below after barrier.
            }

            __syncthreads();   // the ONE barrier per step

            if (w == NTW && lane < EPB) {
                float s = bfc;
#pragma unroll
                for (int j = 0; j < NTW; ++j) s += ypart[wp][j][lane];
                y_lds[tt * 17 + lane] = s;
            }
        }
        __syncthreads();

        for (int i2 = tid; i2 < CH * EPB; i2 += NTH) {
            int ee = i2 / CH, tt = i2 % CH;
            out[(size_t)(e0 + ee) * SEQT + t0 + tt] = y_lds[tt * 17 + ee];
        }
        __syncthreads();
    }
}

extern "C" void kernel_launch(void* const* d_in, const int* in_sizes, int n_in,
                              void* d_out, int out_size, void* d_ws, size_t ws_size,
                              hipStream_t stream) {
    const float* x    = (const float*)d_in[0];
    const float* W_ih = (const float*)d_in[1];
    const float* W_hh = (const float*)d_in[2];
    const float* b_ih = (const float*)d_in[3];
    const float* b_hh = (const float*)d_in[4];
    const float* W_fc = (const float*)d_in[5];
    const float* b_fc = (const float*)d_in[6];
    float* out = (float*)d_out;

    __hip_bfloat16* A_ext = (__hip_bfloat16*)d_ws;   // 208*64*2 = 26.6 KB

    prep_kernel<<<(MR * 64 + 255) / 256, 256, 0, stream>>>(W_hh, A_ext);
    lstm_mfma_kernel<<<4096 / EPB, NTH, 0, stream>>>(x, W_ih, b_ih, b_hh,
                                                     W_fc, b_fc, A_ext, out);
}

// Round 5
// 573.210 us; speedup vs baseline: 4.6755x; 1.0622x over previous
//
#include <hip/hip_runtime.h>
#include <hip/hip_bf16.h>

#define HID   51
#define MR    208          // 204 gate rows padded to 13 tiles of 16
#define SEQT  999
#define CH    111          // 999 = 9 * 111
#define NCH   9
#define EPB   16           // batch elements per block (MFMA N)
#define NTW   13           // tile waves (one 16-row tile each)
#define NTH   896          // 13 tile waves + 1 x/y-service wave
#define BSTR  72           // bcol row stride in halves (144 B: 16B-aligned, free 2-way)

typedef __attribute__((ext_vector_type(8))) short  short8;   // 8 bf16 = 4 VGPRs
typedef __attribute__((ext_vector_type(4))) float  floatx4;

// A_ext[208][64] bf16, row r = 4u+gate, PRE-SCALED by -log2(e) (i,f,o) or
// -2*log2(e) (g) so the MFMA output is directly an exp2 argument.
//   cols 0..50  <- W_hh[gate*51+u][k]
//   col  51     <- W_ih[gate*51+u]      (x folded into the matmul)
//   cols 52..63 <- 0                    (B rows 52..63 are don't-care)
__global__ void prep_kernel(const float* __restrict__ W_hh,
                            const float* __restrict__ W_ih,
                            __hip_bfloat16* __restrict__ A_ext)
{
    const float K1 = 1.442695040889f;
    int idx = blockIdx.x * blockDim.x + threadIdx.x;
    if (idx >= MR * 64) return;
    int r = idx >> 6, k = idx & 63;
    int u = r >> 2, gate = r & 3;
    float s = (gate == 2) ? (-2.f * K1) : (-K1);
    float v = 0.f;
    if (u < HID) {
        if (k < HID)       v = s * W_hh[(gate * HID + u) * HID + k];
        else if (k == 51)  v = s * W_ih[gate * HID + u];
    }
    A_ext[idx] = __float2bfloat16(v);
}

__launch_bounds__(NTH)
__global__ void lstm_mfma_kernel(const float* __restrict__ x,
                                 const float* __restrict__ b_ih,
                                 const float* __restrict__ b_hh,
                                 const float* __restrict__ W_fc,
                                 const float* __restrict__ b_fc,
                                 const __hip_bfloat16* __restrict__ A_ext,
                                 float* __restrict__ out)
{
    // bcol[buf][e*72 + k]: B operand. rows 0..50 = h, row 51 = x_t, row 63 =
    // dump row for the u==51 lane (A col 63 == 0), rest stay 0.
    __shared__ __hip_bfloat16 bcol[2][EPB * BSTR];
    __shared__ float x_lds[(CH + 1) * 17];   // staged with 1 lookahead elem
    __shared__ float y_lds[CH * 17];
    __shared__ float ypart[2][NTW][EPB];

    const int tid  = threadIdx.x;
    const int w    = tid >> 6;    // 0..12 tile waves, 13 = service wave
    const int lane = tid & 63;
    const int e    = lane & 15;   // elem (MFMA col)
    const int g4   = lane >> 4;   // lane group
    const int e0   = blockIdx.x * EPB;
    const int u    = 4 * w + g4;
    const bool tw  = (w < NTW);
    const int wrow = (u < HID) ? u : 63;   // u==51 lane dumps into dead row 63

    const float K1 = 1.442695040889f;

    short8  Afrag0 = {0,0,0,0,0,0,0,0}, Afrag1 = {0,0,0,0,0,0,0,0};
    floatx4 bq = {0.f, 0.f, 0.f, 0.f};
    float   wfc_r = 0.f;
    float   cstS  = 0.f;          // cell state, pre-scaled by -2*log2(e)

    if (tw) {
        int m = w * 16 + e;
        Afrag0 = *(const short8*)&A_ext[m * 64 + g4 * 8];
        Afrag1 = *(const short8*)&A_ext[m * 64 + 32 + g4 * 8];
        if (u < HID) {
#pragma unroll
            for (int gg = 0; gg < 4; ++gg) {
                float s = (gg == 2) ? (-2.f * K1) : (-K1);
                bq[gg] = s * (b_ih[gg * HID + u] + b_hh[gg * HID + u]);
            }
            wfc_r = W_fc[u];
        }
    }

    for (int i = tid; i < EPB * BSTR; i += NTH) {
        bcol[0][i] = __float2bfloat16(0.f);
        bcol[1][i] = __float2bfloat16(0.f);
    }
    __syncthreads();   // RACE FIX: zero-init fully ordered before x0 seed
    // x_0 into step-0's read buffer, row 51 (16 scattered one-time reads)
    if (tid < EPB)
        bcol[0][tid * BSTR + 51] = __float2bfloat16(x[(size_t)(e0 + tid) * SEQT]);
    const float bfc = b_fc[0];

    __syncthreads();

    for (int tc = 0; tc < NCH; ++tc) {
        const int t0 = tc * CH;
        // stage x[t0 .. t0+CH] (CH+1 entries: +1 lookahead for row-51 prewrite)
        for (int i2 = tid; i2 < (CH + 1) * EPB; i2 += NTH) {
            int ee = i2 / (CH + 1), tt = i2 % (CH + 1);
            int t = t0 + tt;
            x_lds[tt * 17 + ee] = (t < SEQT) ? x[(size_t)(e0 + ee) * SEQT + t] : 0.f;
        }
        __syncthreads();

        for (int tt = 0; tt < CH; ++tt) {
            const int t  = t0 + tt;
            const int rp = t & 1, wp = rp ^ 1;

            if (tw) {
                short8 B0 = *(const short8*)&bcol[rp][e * BSTR + g4 * 8];
                short8 B1 = *(const short8*)&bcol[rp][e * BSTR + 32 + g4 * 8];

                // bias in C-input; x-term via B row 51; outputs are exp2 args
                floatx4 acc = __builtin_amdgcn_mfma_f32_16x16x32_bf16(Afrag0, B0, bq, 0, 0, 0);
                acc = __builtin_amdgcn_mfma_f32_16x16x32_bf16(Afrag1, B1, acc, 0, 0, 0);

                float si  = __builtin_amdgcn_rcpf(1.f + __builtin_amdgcn_exp2f(acc[0]));
                float sf  = __builtin_amdgcn_rcpf(1.f + __builtin_amdgcn_exp2f(acc[1]));
                float sgs = __builtin_amdgcn_rcpf(1.f + __builtin_amdgcn_exp2f(acc[2]));
                float so  = __builtin_amdgcn_rcpf(1.f + __builtin_amdgcn_exp2f(acc[3]));
                float sgK = fmaf(-4.f * K1, sgs, 2.f * K1);   // = -2*K1*tanh(g)
                cstS = fmaf(sf, cstS, si * sgK);              // scaled cell state
                float r2 = __builtin_amdgcn_rcpf(1.f + __builtin_amdgcn_exp2f(cstS));
                float h  = so * fmaf(2.f, r2, -1.f);          // o * tanh(c)

                bcol[wp][e * BSTR + wrow] = __float2bfloat16(h);

                float py = wfc_r * h;
                py += __shfl_xor(py, 16);
                py += __shfl_xor(py, 32);
                if (lane < EPB) ypart[wp][w][lane] = py;
            } else if (lane < EPB) {
                // service wave: pre-write x_{t+1} into next buffer's row 51
                bcol[wp][lane * BSTR + 51] =
                    __float2bfloat16(x_lds[(tt + 1) * 17 + lane]);
            }

            __syncthreads();   // the ONE barrier per step

            if (w == NTW && lane < EPB) {
                float s = bfc;
#pragma unroll
                for (int j = 0; j < NTW; ++j) s += ypart[wp][j][lane];
                y_lds[tt * 17 + lane] = s;
            }
        }
        __syncthreads();

        for (int i2 = tid; i2 < CH * EPB; i2 += NTH) {
            int ee = i2 / CH, tt = i2 % CH;
            out[(size_t)(e0 + ee) * SEQT + t0 + tt] = y_lds[tt * 17 + ee];
        }
        __syncthreads();
    }
}

extern "C" void kernel_launch(void* const* d_in, const int* in_sizes, int n_in,
                              void* d_out, int out_size, void* d_ws, size_t ws_size,
                              hipStream_t stream) {
    const float* x    = (const float*)d_in[0];
    const float* W_ih = (const float*)d_in[1];
    const float* W_hh = (const float*)d_in[2];
    const float* b_ih = (const float*)d_in[3];
    const float* b_hh = (const float*)d_in[4];
    const float* W_fc = (const float*)d_in[5];
    const float* b_fc = (const float*)d_in[6];
    float* out = (float*)d_out;

    __hip_bfloat16* A_ext = (__hip_bfloat16*)d_ws;   // 208*64*2 = 26.6 KB

    prep_kernel<<<(MR * 64 + 255) / 256, 256, 0, stream>>>(W_hh, W_ih, A_ext);
    lstm_mfma_kernel<<<4096 / EPB, NTH, 0, stream>>>(x, b_ih, b_hh,
                                                     W_fc, b_fc, A_ext, out);
}

// Round 6
// 479.280 us; speedup vs baseline: 5.5918x; 1.1960x over previous
//
#include <hip/hip_runtime.h>
#include <hip/hip_bf16.h>

#define HID   51
#define MR    208          // 204 gate rows + y row (204) padded to 13 tiles of 16
#define SEQT  999
#define CH    111          // 999 = 9 * 111
#define NCH   9
#define EPB   16           // batch elements per block (MFMA N)
#define NTW   13           // tile waves (one 16-row tile each)
#define NTH   896          // 13 tile waves + 1 x-service wave
#define BSTR  72           // bcol row stride in halves (144 B: 16B-aligned, free 2-way)

typedef __attribute__((ext_vector_type(8))) short  short8;   // 8 bf16 = 4 VGPRs
typedef __attribute__((ext_vector_type(4))) float  floatx4;

// A_ext[208][64] bf16, row r = 4u+gate, PRE-SCALED by -log2(e) (i,f,o) or
// -2*log2(e) (g) so the MFMA output is directly an exp2 argument.
//   rows 0..203: cols 0..50 <- W_hh[gate*51+u][k], col 51 <- W_ih[gate*51+u]
//   row  204   : cols 0..50 <- W_fc[k] UNSCALED  (y_{t-1} falls out of the MFMA)
//   rows 205..207, cols 52..63: zero
__global__ void prep_kernel(const float* __restrict__ W_hh,
                            const float* __restrict__ W_ih,
                            const float* __restrict__ W_fc,
                            __hip_bfloat16* __restrict__ A_ext)
{
    const float K1 = 1.442695040889f;
    int idx = blockIdx.x * blockDim.x + threadIdx.x;
    if (idx >= MR * 64) return;
    int r = idx >> 6, k = idx & 63;
    int u = r >> 2, gate = r & 3;
    float v = 0.f;
    if (r == 204) {
        if (k < HID) v = W_fc[k];
    } else if (u < HID) {
        float s = (gate == 2) ? (-2.f * K1) : (-K1);
        if (k < HID)      v = s * W_hh[(gate * HID + u) * HID + k];
        else if (k == 51) v = s * W_ih[gate * HID + u];
    }
    A_ext[idx] = __float2bfloat16(v);
}

__launch_bounds__(NTH)
__global__ void lstm_mfma_kernel(const float* __restrict__ x,
                                 const float* __restrict__ b_ih,
                                 const float* __restrict__ b_hh,
                                 const float* __restrict__ b_fc,
                                 const __hip_bfloat16* __restrict__ A_ext,
                                 float* __restrict__ out)
{
    // bcol[buf][e*72 + k]: B operand. rows 0..50 = h, row 51 = x_t, row 63 =
    // dump row for u==51 lanes (A col 63 == 0, and the value is forced finite).
    __shared__ __hip_bfloat16 bcol[2][EPB * BSTR];
    __shared__ float x_lds[(CH + 1) * 17];   // +1 lookahead for row-51 prewrite
    __shared__ float y_lds[CH * 17];         // slot tt holds y[t0 + tt - 1]

    const int tid  = threadIdx.x;
    const int w    = tid >> 6;    // 0..12 tile waves, 13 = service wave
    const int lane = tid & 63;
    const int e    = lane & 15;   // elem (MFMA col)
    const int g4   = lane >> 4;   // lane group
    const int e0   = blockIdx.x * EPB;
    const int u    = 4 * w + g4;
    const bool tw  = (w < NTW);
    const bool uok = tw && (u < HID);
    const int wrow = uok ? u : 63;          // u==51 lanes dump into dead row 63
    const bool yln = (w == 12) && (g4 == 3); // lanes owning the y row (204)

    const float K1  = 1.442695040889f;
    const float K2N = -2.885390081777f;     // -2*log2(e)

    short8  Afrag0 = {0,0,0,0,0,0,0,0}, Afrag1 = {0,0,0,0,0,0,0,0};
    floatx4 bq = {0.f, 0.f, 0.f, 0.f};      // stays 0 for u>=51 (incl. y row)
    float   cstS = 0.f;                      // cell state, pre-scaled by -2*log2(e)

    if (tw) {
        int m = w * 16 + e;
        Afrag0 = *(const short8*)&A_ext[m * 64 + g4 * 8];
        Afrag1 = *(const short8*)&A_ext[m * 64 + 32 + g4 * 8];
        if (u < HID) {
#pragma unroll
            for (int gg = 0; gg < 4; ++gg) {
                float s = (gg == 2) ? (-2.f * K1) : (-K1);
                bq[gg] = s * (b_ih[gg * HID + u] + b_hh[gg * HID + u]);
            }
        }
    }

    for (int i = tid; i < EPB * BSTR; i += NTH) {
        bcol[0][i] = __float2bfloat16(0.f);
        bcol[1][i] = __float2bfloat16(0.f);
    }
    __syncthreads();   // zero-init fully ordered before x0 seed (race fix)
    if (tid < EPB)
        bcol[0][tid * BSTR + 51] = __float2bfloat16(x[(size_t)(e0 + tid) * SEQT]);
    const float bfc = b_fc[0];

    __syncthreads();

    for (int tc = 0; tc < NCH; ++tc) {
        const int t0 = tc * CH;
        for (int i2 = tid; i2 < (CH + 1) * EPB; i2 += NTH) {
            int ee = i2 / (CH + 1), tt = i2 % (CH + 1);
            int t = t0 + tt;
            x_lds[tt * 17 + ee] = (t < SEQT) ? x[(size_t)(e0 + ee) * SEQT + t] : 0.f;
        }
        __syncthreads();

        for (int tt = 0; tt < CH; ++tt) {
            const int t  = t0 + tt;
            const int rp = t & 1, wp = rp ^ 1;

            if (tw) {
                short8 B0 = *(const short8*)&bcol[rp][e * BSTR + g4 * 8];
                short8 B1 = *(const short8*)&bcol[rp][e * BSTR + 32 + g4 * 8];

                floatx4 acc = __builtin_amdgcn_mfma_f32_16x16x32_bf16(Afrag0, B0, bq, 0, 0, 0);
                acc = __builtin_amdgcn_mfma_f32_16x16x32_bf16(Afrag1, B1, acc, 0, 0, 0);

                // acc[g] = exp2-args; fused sigmoid/tanh products (3 rcp, 5 exp2)
                float Ei = __builtin_amdgcn_exp2f(acc[0]);
                float Ef = __builtin_amdgcn_exp2f(acc[1]);
                float Eg = __builtin_amdgcn_exp2f(acc[2]);
                float Eo = __builtin_amdgcn_exp2f(acc[3]);
                float sf  = __builtin_amdgcn_rcpf(1.f + Ef);
                float Rig = __builtin_amdgcn_rcpf(fmaf(Ei, Eg, (Ei + Eg) + 1.f));
                float term = (1.f - Eg) * Rig;            // sigma(i)*tanh(g)
                cstS = fmaf(sf, cstS, K2N * term);
                float Ec = __builtin_amdgcn_exp2f(cstS);
                float Roc = __builtin_amdgcn_rcpf(fmaf(Eo, Ec, (Eo + Ec) + 1.f));
                float h = (1.f - Ec) * Roc;               // sigma(o)*tanh(c)

                bcol[wp][e * BSTR + wrow] = __float2bfloat16(uok ? h : 0.f);
                if (yln) y_lds[tt * 17 + e] = acc[0] + bfc;   // y[t-1], free from row 204
            } else if (lane < EPB) {
                // service wave: pre-write x_{t+1} into next buffer's row 51
                bcol[wp][lane * BSTR + 51] =
                    __float2bfloat16(x_lds[(tt + 1) * 17 + lane]);
            }

            __syncthreads();   // the ONE barrier per step
        }
        __syncthreads();

        // flush y[t0-1 .. t0+CH-2] (slot tt <-> t0+tt-1); skip t = -1
        for (int i2 = tid; i2 < CH * EPB; i2 += NTH) {
            int ee = i2 / CH, tt = i2 % CH;
            int t = t0 + tt - 1;
            if (t >= 0)
                out[(size_t)(e0 + ee) * SEQT + t] = y_lds[tt * 17 + ee];
        }
        __syncthreads();
    }

    // epilogue: y[998] from one extra MFMA pass over h_998 (in bcol[1])
    if (w == 12) {
        short8 B0 = *(const short8*)&bcol[1][e * BSTR + g4 * 8];
        short8 B1 = *(const short8*)&bcol[1][e * BSTR + 32 + g4 * 8];
        floatx4 acc = __builtin_amdgcn_mfma_f32_16x16x32_bf16(Afrag0, B0, bq, 0, 0, 0);
        acc = __builtin_amdgcn_mfma_f32_16x16x32_bf16(Afrag1, B1, acc, 0, 0, 0);
        if (g4 == 3)
            out[(size_t)(e0 + e) * SEQT + (SEQT - 1)] = acc[0] + bfc;
    }
}

extern "C" void kernel_launch(void* const* d_in, const int* in_sizes, int n_in,
                              void* d_out, int out_size, void* d_ws, size_t ws_size,
                              hipStream_t stream) {
    const float* x    = (const float*)d_in[0];
    const float* W_ih = (const float*)d_in[1];
    const float* W_hh = (const float*)d_in[2];
    const float* b_ih = (const float*)d_in[3];
    const float* b_hh = (const float*)d_in[4];
    const float* W_fc = (const float*)d_in[5];
    const float* b_fc = (const float*)d_in[6];
    float* out = (float*)d_out;

    __hip_bfloat16* A_ext = (__hip_bfloat16*)d_ws;   // 208*64*2 = 26.6 KB

    prep_kernel<<<(MR * 64 + 255) / 256, 256, 0, stream>>>(W_hh, W_ih, W_fc, A_ext);
    lstm_mfma_kernel<<<4096 / EPB, NTH, 0, stream>>>(x, b_ih, b_hh,
                                                     b_fc, A_ext, out);
}